// Round 6
// baseline (115.739 us; speedup 1.0000x reference)
//
#include <hip/hip_runtime.h>

// FOFE windowed encoder — "memset-order" writer.
// out[b,c,i,t] = z[t-1] - alpha^{w_i} * z[t-1-w_i];  z[t]=alpha*z[t-1]+x[t]
// w_i = i (i<48), w_48 = 64. out shape (8,512,49,513) f32.
//
// Each block owns TWO complete (b,c) slabs = 50274 contiguous floats and
// writes them in LINEAR address order as 16B-aligned f32x4 (after <=2-elem
// peel) — byte-identical store stream to fillBufferAligned, so every 64B
// line is fully covered by temporally-adjacent stores (no partial-line
// first touches). The (i,t) structure is recovered by constant-division
// index decode; ~0.8% of f32x4s straddle a row boundary -> scalar slow path.

#define CC 512
#define LL 512
#define NW 49
#define LO 513
#define SLAB (NW * LO)        // 25137 floats per (b,c)
#define R0F (2 * SLAB)        // 50274 floats per block
#define ZOFF 69               // z[q] lives at k = ZOFF + q; zeros for q<0
#define ZROW 640              // swizzle-safe storage (591 used)

typedef float f32x4 __attribute__((ext_vector_type(4)));

// XOR-swizzle for stride-4 lane access: inject idx bits [6:5] into bank bits
// [1:0] -> 2 lanes/bank (free, m136). Involution, bijective on [0,640).
__device__ __forceinline__ int swz(int i) { return i ^ ((i >> 5) & 3); }

__global__ __launch_bounds__(256)
void fofe_kernel(const float* __restrict__ x,
                 const float* __restrict__ alpha,
                 float* __restrict__ out)
{
    __shared__ float zs[2][ZROW];
    __shared__ float lut[2][NW];      // alpha^{w_i} per local row

    const int tid  = threadIdx.x;
    const int wid  = tid >> 6;
    const int lane = tid & 63;
    const int blk  = blockIdx.x;

    // ---------- stage: scan rows (waves 0,1), pow-LUT (tid<98) ----------
    if (wid < 2) {
        const int row = blk * 2 + wid;
        const float al = alpha[row & (CC - 1)];
        const float* xr = x + (size_t)row * LL;

        const f32x4 xv0 = reinterpret_cast<const f32x4*>(xr)[lane * 2];
        const f32x4 xv1 = reinterpret_cast<const f32x4*>(xr)[lane * 2 + 1];
        const float xe[8] = {xv0.x, xv0.y, xv0.z, xv0.w,
                             xv1.x, xv1.y, xv1.z, xv1.w};
        float l[8];
        {
            float s = 0.f;
            #pragma unroll
            for (int m = 0; m < 8; ++m) { s = fmaf(al, s, xe[m]); l[m] = s; }
        }
        float pw[8];
        {
            float p = al;
            #pragma unroll
            for (int m = 0; m < 8; ++m) { pw[m] = p; p *= al; }
        }
        float A = pw[7], S = l[7];
        #pragma unroll
        for (int off = 1; off < 64; off <<= 1) {
            const float Ap = __shfl_up(A, off);
            const float Sp = __shfl_up(S, off);
            if (lane >= off) { S = fmaf(A, Sp, S); A = A * Ap; }
        }
        float carry = __shfl_up(S, 1);
        if (lane == 0) carry = 0.f;

        float* z = zs[wid];
        z[swz(lane)] = 0.f;                                   // k = 0..63
        if (lane < ZOFF - 64) z[swz(64 + lane)] = 0.f;        // k = 64..68
        if (lane < 11) z[swz(ZOFF + LL + lane)] = 0.f;        // k = 581..591
        #pragma unroll
        for (int m = 0; m < 8; ++m)
            z[swz(ZOFF + lane * 8 + m)] = fmaf(pw[m], carry, l[m]);
    }
    if (tid < 2 * NW) {
        const int r = tid / NW, i = tid - r * NW;
        const int row = blk * 2 + r;
        const float al = alpha[row & (CC - 1)];
        const int w = (i < 48) ? i : 64;
        float p = 1.f, m = al;
        #pragma unroll
        for (int b = 0; b < 7; ++b) { if (w & (1 << b)) p *= m; m *= m; }
        lut[r][i] = p;
    }
    __syncthreads();

    // ---------- linear writer over the 2-slab region ----------
    float* base = out + (size_t)blk * R0F;
    // element phase of base: (blk*50274) & 3 = (2*blk) & 3  -> peel 0 or 2
    const int peel = (4 - ((2 * blk) & 3)) & 3;
    const int nf4  = (R0F - peel) >> 2;
    const int ntail = (R0F - peel) & 3;

    // scalar slow-path evaluator for one block-local element e
    auto eval1 = [&](int e) -> float {
        const int r01 = (e >= SLAB);
        const int e2  = e - r01 * SLAB;
        const unsigned i = (unsigned)e2 / 513u;
        const int t   = e2 - (int)i * 513;
        const int w   = (i < 48u) ? (int)i : 64;
        return fmaf(-lut[r01][i], zs[r01][swz(ZOFF - 1 + t - w)],
                    zs[r01][swz(ZOFF - 1 + t)]);
    };

    if (tid < peel)          base[tid] = eval1(tid);
    if (tid < ntail)         base[peel + 4 * nf4 + tid] = eval1(peel + 4 * nf4 + tid);

    for (int f = tid; f < nf4; f += 256) {
        const int el  = peel + 4 * f;
        const int r01 = (el >= SLAB);
        const int e2  = el - r01 * SLAB;
        const unsigned i = (unsigned)e2 / 513u;
        const int t   = e2 - (int)i * 513;

        if (t <= 509) {                       // fast path: one (row,i) for all 4
            const float apw = lut[r01][i];
            const float* z = zs[r01];
            const int k0 = ZOFF - 1 + t;
            const int w  = (i < 48u) ? (int)i : 64;
            f32x4 v;
            v.x = fmaf(-apw, z[swz(k0     - w)], z[swz(k0    )]);
            v.y = fmaf(-apw, z[swz(k0 + 1 - w)], z[swz(k0 + 1)]);
            v.z = fmaf(-apw, z[swz(k0 + 2 - w)], z[swz(k0 + 2)]);
            v.w = fmaf(-apw, z[swz(k0 + 3 - w)], z[swz(k0 + 3)]);
            *reinterpret_cast<f32x4*>(base + el) = v;       // 16B-aligned
        } else {                              // straddles a row boundary
            f32x4 v;
            v.x = eval1(el);
            v.y = eval1(el + 1);
            v.z = eval1(el + 2);
            v.w = eval1(el + 3);
            *reinterpret_cast<f32x4*>(base + el) = v;
        }
    }
}

extern "C" void kernel_launch(void* const* d_in, const int* in_sizes, int n_in,
                              void* d_out, int out_size, void* d_ws, size_t ws_size,
                              hipStream_t stream)
{
    const float* x     = (const float*)d_in[0];
    const float* alpha = (const float*)d_in[1];
    float* out = (float*)d_out;

    const int grid = (8 * CC) / 2;     // 2048 blocks, 2 slabs each
    fofe_kernel<<<grid, 256, 0, stream>>>(x, alpha, out);
}

// Round 7
// 85.901 us; speedup vs baseline: 1.3474x; 1.3474x over previous
//
#include <hip/hip_runtime.h>

// FOFE windowed encoder — sweep-ordered writer.
// out[b,c,i,t] = z[t-1] - alpha^{w_i} * z[t-1-w_i];  z[t]=alpha*z[t-1]+x[t]
// w_i = i (i<48), w_48 = 64. out shape (8,512,49,513) f32 (~412 MB).
//
// Theory: prior kernels (91-116 us) were capped ~4.5 TB/s by DRAM row-buffer
// thrash: 1024-2048 concurrent blocks -> write window 200-412 MB -> ~100 open
// row candidates/bank. fillBufferAligned (6.8 TB/s) sweeps a ~2 MB window.
// Here: 256 blocks (1/CU), block b writes slabs g = tau*256 + b for tau=0..15
// -> concurrently-active slabs are CONTIGUOUS (~25 MB sweeping window).
// All 16 scans done upfront into LDS; then an uninterrupted store stream.

#define CC 512
#define LL 512
#define NW 49
#define LO 513
#define SLAB (NW * LO)        // 25137 floats per (b,c)
#define GRID 256
#define NTAU 16               // 4096 slabs / 256 blocks
#define ZOFF 65               // z[q] at k = ZOFF + q; k in [0,577); zeros k<65
#define ZROW 640

typedef float f32x4 __attribute__((ext_vector_type(4)));

// XOR-swizzle for stride-4 lane access: inject idx bits [6:5] into bank bits
// [1:0] -> 2 lanes/bank (free, m136). Involution, bijective on [0,640).
__device__ __forceinline__ int swz(int i) { return i ^ ((i >> 5) & 3); }

__global__ __launch_bounds__(512)
void fofe_kernel(const float* __restrict__ x,
                 const float* __restrict__ alpha,
                 float* __restrict__ out)
{
    __shared__ float zs[NTAU][ZROW];   // 40 KB

    const int tid  = threadIdx.x;
    const int wid  = tid >> 6;         // 0..7
    const int lane = tid & 63;
    const int blk  = blockIdx.x;

    // ---------- phase 1: all 16 row-scans upfront (wave w: tau = w, w+8) ----
    for (int tau = wid; tau < NTAU; tau += 8) {
        const int g = tau * GRID + blk;            // global slab / row index
        const float al = alpha[g & (CC - 1)];
        const float* xr = x + (size_t)g * LL;

        const f32x4 xv0 = reinterpret_cast<const f32x4*>(xr)[lane * 2];
        const f32x4 xv1 = reinterpret_cast<const f32x4*>(xr)[lane * 2 + 1];
        const float xe[8] = {xv0.x, xv0.y, xv0.z, xv0.w,
                             xv1.x, xv1.y, xv1.z, xv1.w};
        float l[8];
        {
            float s = 0.f;
            #pragma unroll
            for (int m = 0; m < 8; ++m) { s = fmaf(al, s, xe[m]); l[m] = s; }
        }
        float pw[8];                               // alpha^{m+1}
        {
            float p = al;
            #pragma unroll
            for (int m = 0; m < 8; ++m) { pw[m] = p; p *= al; }
        }
        float A = pw[7], S = l[7];
        #pragma unroll
        for (int off = 1; off < 64; off <<= 1) {
            const float Ap = __shfl_up(A, off);
            const float Sp = __shfl_up(S, off);
            if (lane >= off) { S = fmaf(A, Sp, S); A = A * Ap; }
        }
        float carry = __shfl_up(S, 1);
        if (lane == 0) carry = 0.f;

        float* z = zs[tau];
        z[swz(lane)] = 0.f;                        // k = 0..63
        if (lane == 0) z[swz(64)] = 0.f;           // k = 64   (z[-1])
        #pragma unroll
        for (int m = 0; m < 8; ++m)
            z[swz(ZOFF + lane * 8 + m)] = fmaf(pw[m], carry, l[m]);
    }
    __syncthreads();

    // ---------- phase 2: sweep-write slabs tau = 0..15 ----------
    for (int tau = 0; tau < NTAU; ++tau) {
        const int g = tau * GRID + blk;
        const float al = alpha[g & (CC - 1)];
        const float* z = zs[tau];
        float* oslab = out + (size_t)g * SLAB;

        const float a2  = al * al, a4 = a2 * a2, a8 = a4 * a4;
        const float a16 = a8 * a8;
        const float a64 = (a16 * a16) * (a16 * a16);

        // p = alpha^wid (3-bit exponent by squaring)
        float p = 1.f;
        {
            float m = al;
            #pragma unroll
            for (int b = 0; b < 3; ++b) { if (wid & (1 << b)) p *= m; m *= m; }
        }

        // wave w writes rows i = w, w+8, ... (wave 0 also gets i=48 / w=64)
        for (int i = wid; i < NW; i += 8) {
            const int   w   = (i < 48) ? i : 64;
            const float apw = (i < 48) ? p : a64;
            float* op = oslab + i * LO;
            // element phase of op = (g + i) & 3   (25137%4==1, 513%4==1)
            const int q    = (g + i) & 3;
            const int peel = (4 - q) & 3;
            const int k0b  = ZOFF - 1;             // + t gives z[t-1]

            if (lane < peel)
                op[lane] = fmaf(-apw, z[swz(k0b + lane - w)], z[swz(k0b + lane)]);

            const int nf4  = (LO - peel) >> 2;
            const int tail = (LO - peel) & 3;
            for (int f = lane; f < nf4; f += 64) {
                const int t0 = peel + 4 * f;
                const int k0 = k0b + t0;
                f32x4 v;
                v.x = fmaf(-apw, z[swz(k0     - w)], z[swz(k0    )]);
                v.y = fmaf(-apw, z[swz(k0 + 1 - w)], z[swz(k0 + 1)]);
                v.z = fmaf(-apw, z[swz(k0 + 2 - w)], z[swz(k0 + 2)]);
                v.w = fmaf(-apw, z[swz(k0 + 3 - w)], z[swz(k0 + 3)]);
                *reinterpret_cast<f32x4*>(op + t0) = v;    // 16B-aligned
            }
            if (lane < tail) {
                const int t = peel + 4 * nf4 + lane;
                op[t] = fmaf(-apw, z[swz(k0b + t - w)], z[swz(k0b + t)]);
            }
            p *= a8;
        }
        __syncthreads();   // keep the block's waves in the same slab window
    }
}

extern "C" void kernel_launch(void* const* d_in, const int* in_sizes, int n_in,
                              void* d_out, int out_size, void* d_ws, size_t ws_size,
                              hipStream_t stream)
{
    const float* x     = (const float*)d_in[0];
    const float* alpha = (const float*)d_in[1];
    float* out = (float*)d_out;

    fofe_kernel<<<GRID, 512, 0, stream>>>(x, alpha, out);
}